// Round 5
// baseline (1337.876 us; speedup 1.0000x reference)
//
#include <hip/hip_runtime.h>
#include <hip/hip_bf16.h>

// VectorQuantizer on MI355X (gfx950). Inputs fp32, output buffer fp32.
// z: [64,256,32,32] f32; E: [1024,256] f32.
// out (f32): z_q[16777216] | loss[1] | indices[65536] (float(idx), bf16-roundtrip)
//
// Argmin must match the np float32 reference BIT-EXACTLY in its tie behavior:
// d = fp32(fp32(Sz + Se[k]) - 2*dot[k]) is quantized at ulp(~256)=2.3e-5, so
// ~0.4% of rows tie on the grid and np.argmin picks the FIRST index.
// Pipeline: Se (np-pairwise-exact) -> bf16 MFMA GEMM + top-2 (margin 2.5e-4)
// -> np-fp32-emulated refine of flagged rows (sequential-FMA dot like BLAS)
// -> gather z_q + fused loss -> finalize.
//
// ws: [0,4) loss f32 | [4,8) refine cnt | [64,4160) Se[1024] | [4352,69888) list

typedef __attribute__((ext_vector_type(8))) short short8;
typedef __attribute__((ext_vector_type(4))) float floatx4;

#define MARGIN 2.5e-4f
#define REFINE_CAP 16384u
#define RGROUP 16
#define IDX_OFF 16777217

__device__ __forceinline__ unsigned short f2b(float f) {
    union { float f; unsigned int i; } x; x.f = f;
    unsigned int i = x.i;
    unsigned int r = (i + 0x7fffu + ((i >> 16) & 1u)) >> 16;  // RN-even
    return (unsigned short)r;
}
__device__ __forceinline__ float b2f(unsigned short u) {
    union { unsigned int i; float f; } x; x.i = ((unsigned int)u) << 16; return x.f;
}

// numpy pairwise sum of squares, n=256 contiguous: split 128+128, each block
// 8 scalar accumulators over stride-8, combine ((r0+r1)+(r2+r3))+((r4+r5)+(r6+r7)).
// __fmul_rn/__fadd_rn prevent fma contraction (np adds the ROUNDED squares).
__device__ __forceinline__ float np_pairwise_sumsq(const float* __restrict__ a) {
    float blk[2];
    #pragma unroll
    for (int h = 0; h < 2; h++) {
        const float* p = a + h * 128;
        float r0 = __fmul_rn(p[0], p[0]), r1 = __fmul_rn(p[1], p[1]);
        float r2 = __fmul_rn(p[2], p[2]), r3 = __fmul_rn(p[3], p[3]);
        float r4 = __fmul_rn(p[4], p[4]), r5 = __fmul_rn(p[5], p[5]);
        float r6 = __fmul_rn(p[6], p[6]), r7 = __fmul_rn(p[7], p[7]);
        for (int i = 8; i < 128; i += 8) {
            r0 = __fadd_rn(r0, __fmul_rn(p[i + 0], p[i + 0]));
            r1 = __fadd_rn(r1, __fmul_rn(p[i + 1], p[i + 1]));
            r2 = __fadd_rn(r2, __fmul_rn(p[i + 2], p[i + 2]));
            r3 = __fadd_rn(r3, __fmul_rn(p[i + 3], p[i + 3]));
            r4 = __fadd_rn(r4, __fmul_rn(p[i + 4], p[i + 4]));
            r5 = __fadd_rn(r5, __fmul_rn(p[i + 5], p[i + 5]));
            r6 = __fadd_rn(r6, __fmul_rn(p[i + 6], p[i + 6]));
            r7 = __fadd_rn(r7, __fmul_rn(p[i + 7], p[i + 7]));
        }
        blk[h] = __fadd_rn(__fadd_rn(__fadd_rn(r0, r1), __fadd_rn(r2, r3)),
                           __fadd_rn(__fadd_rn(r4, r5), __fadd_rn(r6, r7)));
    }
    return __fadd_rn(blk[0], blk[1]);
}

// ---------------- kernel 1: Se[k] = np-exact sum(e_k^2) ----------------
__global__ __launch_bounds__(256) void se_kernel(const float* __restrict__ E,
                                                 float* __restrict__ Se) {
    int k = blockIdx.x * 256 + threadIdx.x;   // 4 blocks -> 1024 threads
    Se[k] = np_pairwise_sumsq(E + k * 256);
}

// ---------------- kernel 2: bf16 MFMA GEMM + fused top-2 argmax ----------------
// 1024 blocks (64 z-rows each), 256 threads = 4 waves.
__global__ __launch_bounds__(256) void gemm_argmin(const float* __restrict__ Z,
                                                   const float* __restrict__ E,
                                                   const float* __restrict__ Se,
                                                   int* __restrict__ idx_out,
                                                   int* __restrict__ refine_list,
                                                   unsigned int* __restrict__ refine_cnt) {
    __shared__ __align__(16) unsigned short Blds[64 * 264];  // 528B padded rows
    const int t  = threadIdx.x;
    const int w  = t >> 6;
    const int l  = t & 63;
    const int lo = l & 15;
    const int hi = l >> 4;
    const int m0 = blockIdx.x * 64;
    const int b  = m0 >> 10;
    const int hw = (m0 & 1023) + w * 16 + lo;
    const float* zs = Z + b * 262144 + hw;

    short8 af[8];
    #pragma unroll
    for (int ks = 0; ks < 8; ks++) {
        #pragma unroll
        for (int j = 0; j < 8; j++)
            af[ks][j] = (short)f2b(zs[(ks * 32 + hi * 8 + j) * 1024]);
    }

    floatx4 acc[4];
    #pragma unroll
    for (int nf = 0; nf < 4; nf++) acc[nf] = (floatx4){0.f, 0.f, 0.f, 0.f};

    float v1[4], v2[4]; int i1[4];
    #pragma unroll
    for (int r = 0; r < 4; r++) { v1[r] = -1e30f; v2[r] = -1e30f; i1[r] = 0; }

    for (int nt = 0; nt < 16; nt++) {
        __syncthreads();
        const float* Eb = E + nt * 64 * 256;
        #pragma unroll
        for (int i = 0; i < 16; i++) {
            int chunk = i * 256 + t;
            int row = chunk >> 6, x = chunk & 63;
            float4 v = *(const float4*)(Eb + row * 256 + x * 4);
            unsigned int p0 = (unsigned int)f2b(v.x) | ((unsigned int)f2b(v.y) << 16);
            unsigned int p1 = (unsigned int)f2b(v.z) | ((unsigned int)f2b(v.w) << 16);
            *(uint2*)((char*)Blds + row * 528 + x * 8) = make_uint2(p0, p1);
        }
        __syncthreads();

        #pragma unroll
        for (int ks = 0; ks < 8; ks++) {
            #pragma unroll
            for (int nf = 0; nf < 4; nf++) {
                const short8* bp = (const short8*)((const char*)Blds +
                                    (nf * 16 + lo) * 528 + (ks * 32 + hi * 8) * 2);
                acc[nf] = __builtin_amdgcn_mfma_f32_16x16x32_bf16(af[ks], *bp, acc[nf], 0, 0, 0);
            }
        }

        #pragma unroll
        for (int nf = 0; nf < 4; nf++) {
            int n = nt * 64 + nf * 16 + lo;
            float h = 0.5f * Se[n];
            #pragma unroll
            for (int r = 0; r < 4; r++) {
                float s = acc[nf][r] - h;
                if (s > v1[r])      { v2[r] = v1[r]; v1[r] = s; i1[r] = n; }
                else if (s > v2[r]) { v2[r] = s; }
                acc[nf][r] = 0.f;
            }
        }
    }

    #pragma unroll
    for (int r = 0; r < 4; r++) {
        float a1 = v1[r], a2 = v2[r]; int ai = i1[r];
        #pragma unroll
        for (int mask = 1; mask < 16; mask <<= 1) {
            float o1 = __shfl_xor(a1, mask);
            int   oi = __shfl_xor(ai, mask);
            float o2 = __shfl_xor(a2, mask);
            if (o1 > a1 || (o1 == a1 && oi < ai)) {
                a2 = fmaxf(a1, o2); a1 = o1; ai = oi;
            } else {
                a2 = fmaxf(a2, o1);
            }
        }
        if (lo == 0) {
            int m = m0 + w * 16 + hi * 4 + r;
            idx_out[m] = ai;
            if (a1 - a2 < MARGIN) {
                unsigned int p = atomicAdd(refine_cnt, 1u);
                if (p < REFINE_CAP) refine_list[p] = m;
            }
        }
    }
}

// ---------------- kernel 3: np-fp32-emulated refine of flagged rows ----------------
// Emulates: d = fp32(fp32(Sz + Se[k]) - 2*dot[k]), dot = sequential fp32 FMA
// (BLAS microkernel order), argmin = first index (strict <, k ascending).
// 16 rows per block; thread (r=t>>4, j=t&15) covers k = j + 16q ascending.
__global__ __launch_bounds__(256) void refine_np(const float* __restrict__ Z,
                                                 const float* __restrict__ E,
                                                 const float* __restrict__ Se,
                                                 const unsigned int* __restrict__ cnt,
                                                 const int* __restrict__ list,
                                                 int* __restrict__ idx_out) {
    __shared__ float zl[RGROUP * 260];
    __shared__ float sz[RGROUP];
    __shared__ int rowid[RGROUP];
    unsigned int C = *cnt;
    if (C > REFINE_CAP) C = REFINE_CAP;
    const int t = threadIdx.x;
    const int r = t >> 4;
    const int j = t & 15;
    for (unsigned int base = blockIdx.x * RGROUP; base < C; base += gridDim.x * RGROUP) {
        int nrows = min(RGROUP, (int)(C - base));
        __syncthreads();
        if (t < RGROUP) rowid[t] = list[base + (t < nrows ? t : 0)];
        __syncthreads();
        #pragma unroll
        for (int i = 0; i < RGROUP; i++) {
            int n = rowid[i];
            zl[i * 260 + t] = Z[(n >> 10) * 262144 + t * 1024 + (n & 1023)];
        }
        __syncthreads();
        if (t < RGROUP) sz[t] = np_pairwise_sumsq(&zl[t * 260]);
        __syncthreads();

        const float* zrow = &zl[r * 260];
        float szr = sz[r];
        float bd = 3.4e38f; int bi = 0x7fffffff;
        for (int g = 0; g < 16; g++) {
            int k0 = j + 64 * g;              // chunk: k0, k0+16, k0+32, k0+48
            const float* e0 = E + (size_t)k0 * 256;
            const float* e1 = e0 + 16 * 256;
            const float* e2 = e0 + 32 * 256;
            const float* e3 = e0 + 48 * 256;
            float a0 = 0.f, a1 = 0.f, a2 = 0.f, a3 = 0.f;
            for (int c = 0; c < 256; c += 4) {
                float4 z4 = *(const float4*)(zrow + c);
                float4 w0 = *(const float4*)(e0 + c);
                float4 w1 = *(const float4*)(e1 + c);
                float4 w2 = *(const float4*)(e2 + c);
                float4 w3 = *(const float4*)(e3 + c);
                a0 = __fmaf_rn(z4.x, w0.x, a0); a0 = __fmaf_rn(z4.y, w0.y, a0);
                a0 = __fmaf_rn(z4.z, w0.z, a0); a0 = __fmaf_rn(z4.w, w0.w, a0);
                a1 = __fmaf_rn(z4.x, w1.x, a1); a1 = __fmaf_rn(z4.y, w1.y, a1);
                a1 = __fmaf_rn(z4.z, w1.z, a1); a1 = __fmaf_rn(z4.w, w1.w, a1);
                a2 = __fmaf_rn(z4.x, w2.x, a2); a2 = __fmaf_rn(z4.y, w2.y, a2);
                a2 = __fmaf_rn(z4.z, w2.z, a2); a2 = __fmaf_rn(z4.w, w2.w, a2);
                a3 = __fmaf_rn(z4.x, w3.x, a3); a3 = __fmaf_rn(z4.y, w3.y, a3);
                a3 = __fmaf_rn(z4.z, w3.z, a3); a3 = __fmaf_rn(z4.w, w3.w, a3);
            }
            float d0 = __fsub_rn(__fadd_rn(szr, Se[k0]),      __fmul_rn(2.f, a0));
            float d1 = __fsub_rn(__fadd_rn(szr, Se[k0 + 16]), __fmul_rn(2.f, a1));
            float d2 = __fsub_rn(__fadd_rn(szr, Se[k0 + 32]), __fmul_rn(2.f, a2));
            float d3 = __fsub_rn(__fadd_rn(szr, Se[k0 + 48]), __fmul_rn(2.f, a3));
            if (d0 < bd) { bd = d0; bi = k0; }
            if (d1 < bd) { bd = d1; bi = k0 + 16; }
            if (d2 < bd) { bd = d2; bi = k0 + 32; }
            if (d3 < bd) { bd = d3; bi = k0 + 48; }
        }
        #pragma unroll
        for (int mask = 1; mask < 16; mask <<= 1) {
            float od = __shfl_xor(bd, mask);
            int   oi = __shfl_xor(bi, mask);
            if (od < bd || (od == bd && oi < bi)) { bd = od; bi = oi; }
        }
        if (j == 0 && r < nrows) idx_out[rowid[r]] = bi;
    }
}

// ---------------- kernel 4: gather z_q (f32 out), fused loss ----------------
__global__ __launch_bounds__(256) void gather_loss(const float* __restrict__ Z,
                                                   const float* __restrict__ E,
                                                   const int* __restrict__ idx,
                                                   float* __restrict__ out,
                                                   float* __restrict__ loss) {
    __shared__ int nl[1024];
    __shared__ float rs[256];
    const int t = threadIdx.x;
    const int blk = blockIdx.x;
    const int e0 = blk * 8192;
    const int b = blk >> 5;
    #pragma unroll
    for (int i = 0; i < 4; i++) nl[t + i * 256] = idx[b * 1024 + t + i * 256];
    __syncthreads();
    float ls = 0.f;
    #pragma unroll 4
    for (int i = 0; i < 32; i++) {
        int e = e0 + i * 256 + t;
        int hw = e & 1023;
        int c  = (e >> 10) & 255;
        float q = E[nl[hw] * 256 + c];
        out[e] = q;
        float d = q - Z[e];
        ls += d * d;
    }
    rs[t] = ls; __syncthreads();
    for (int s = 128; s > 0; s >>= 1) { if (t < s) rs[t] += rs[t + s]; __syncthreads(); }
    if (t == 0) atomicAdd(loss, rs[0]);
}

// ---------------- kernel 5: finalize loss + indices i32 -> float in place ----------------
__global__ __launch_bounds__(256) void finalize(const float* __restrict__ loss,
                                                float* __restrict__ out) {
    int g = blockIdx.x * 256 + threadIdx.x;
    if (g == 0) out[16777216] = 1.25f * (*loss) / 16777216.f;
    int raw = ((const int*)(out + IDX_OFF))[g];
    out[IDX_OFF + g] = b2f(f2b((float)raw));  // bf16 round-trip matches bf16-cast ref
}

extern "C" void kernel_launch(void* const* d_in, const int* in_sizes, int n_in,
                              void* d_out, int out_size, void* d_ws, size_t ws_size,
                              hipStream_t stream) {
    const float* Z = (const float*)d_in[0];
    const float* E = (const float*)d_in[1];
    float* out = (float*)d_out;
    char* ws = (char*)d_ws;
    float*        loss = (float*)ws;
    unsigned int* cnt  = (unsigned int*)(ws + 4);
    float*        Se   = (float*)(ws + 64);
    int*          list = (int*)(ws + 4352);
    int*          idx  = (int*)(out + IDX_OFF);

    hipMemsetAsync(ws, 0, 8, stream);
    se_kernel<<<4, 256, 0, stream>>>(E, Se);
    gemm_argmin<<<1024, 256, 0, stream>>>(Z, E, Se, idx, list, cnt);
    refine_np<<<512, 256, 0, stream>>>(Z, E, Se, cnt, list, idx);
    gather_loss<<<2048, 256, 0, stream>>>(Z, E, idx, out, loss);
    finalize<<<256, 256, 0, stream>>>(loss, out);
}

// Round 6
// 620.051 us; speedup vs baseline: 2.1577x; 2.1577x over previous
//
#include <hip/hip_runtime.h>
#include <hip/hip_bf16.h>

// VectorQuantizer on MI355X (gfx950). Inputs fp32, output buffer fp32.
// z: [64,256,32,32] f32; E: [1024,256] f32.
// out (f32): z_q[16777216] | loss[1] | indices[65536] (float(idx), bf16-roundtrip)
//
// R6: replace blanket full-refine (925 us, 69% of runtime) with exact candidate
// enumeration. Per row: per-lane top-2 + ballots give either (a) unique winner,
// (b) small candidate set evaluated np-exactly INLINE in the GEMM epilogue, or
// (c) rare "lane may hide a 3rd candidate" rows -> LDS-staged full np-exact
// refine. Coverage identical to R5 (which passed); np arithmetic emulation
// (pairwise sumsq, sequential-FMA dot, fp32 rounding, first-index argmin)
// identical to R5's validated refine.
//
// ws: [0,4) loss f32 | [4,8) full cnt | [64,4160) Se[1024] | [4352,+32K) full list

typedef __attribute__((ext_vector_type(8))) short short8;
typedef __attribute__((ext_vector_type(4))) float floatx4;

#define MARGIN 2.5e-4f
#define FULL_CAP 8192u
#define IDX_OFF 16777217

__device__ __forceinline__ unsigned short f2b(float f) {
    union { float f; unsigned int i; } x; x.f = f;
    unsigned int i = x.i;
    unsigned int r = (i + 0x7fffu + ((i >> 16) & 1u)) >> 16;  // RN-even
    return (unsigned short)r;
}
__device__ __forceinline__ float b2f(unsigned short u) {
    union { unsigned int i; float f; } x; x.i = ((unsigned int)u) << 16; return x.f;
}
__device__ __forceinline__ unsigned int bf2bits(__hip_bfloat162 h) {
    union { __hip_bfloat162 h; unsigned int u; } x; x.h = h; return x.u;
}

// numpy pairwise sum of squares, n=256 contiguous: 128+128, each with 8
// stride-8 accumulators, combine ((r0+r1)+(r2+r3))+((r4+r5)+(r6+r7)).
__device__ __forceinline__ float np_pairwise_sumsq(const float* __restrict__ a) {
    float blk[2];
    #pragma unroll
    for (int h = 0; h < 2; h++) {
        const float* p = a + h * 128;
        float r0 = __fmul_rn(p[0], p[0]), r1 = __fmul_rn(p[1], p[1]);
        float r2 = __fmul_rn(p[2], p[2]), r3 = __fmul_rn(p[3], p[3]);
        float r4 = __fmul_rn(p[4], p[4]), r5 = __fmul_rn(p[5], p[5]);
        float r6 = __fmul_rn(p[6], p[6]), r7 = __fmul_rn(p[7], p[7]);
        for (int i = 8; i < 128; i += 8) {
            r0 = __fadd_rn(r0, __fmul_rn(p[i + 0], p[i + 0]));
            r1 = __fadd_rn(r1, __fmul_rn(p[i + 1], p[i + 1]));
            r2 = __fadd_rn(r2, __fmul_rn(p[i + 2], p[i + 2]));
            r3 = __fadd_rn(r3, __fmul_rn(p[i + 3], p[i + 3]));
            r4 = __fadd_rn(r4, __fmul_rn(p[i + 4], p[i + 4]));
            r5 = __fadd_rn(r5, __fmul_rn(p[i + 5], p[i + 5]));
            r6 = __fadd_rn(r6, __fmul_rn(p[i + 6], p[i + 6]));
            r7 = __fadd_rn(r7, __fmul_rn(p[i + 7], p[i + 7]));
        }
        blk[h] = __fadd_rn(__fadd_rn(__fadd_rn(r0, r1), __fadd_rn(r2, r3)),
                           __fadd_rn(__fadd_rn(r4, r5), __fadd_rn(r6, r7)));
    }
    return __fadd_rn(blk[0], blk[1]);
}

// ---------------- kernel 1: Se[k] = np-exact sum(e_k^2) ----------------
__global__ __launch_bounds__(256) void se_kernel(const float* __restrict__ E,
                                                 float* __restrict__ Se) {
    int k = blockIdx.x * 256 + threadIdx.x;
    Se[k] = np_pairwise_sumsq(E + k * 256);
}

// ---------------- kernel 2: bf16 MFMA GEMM + exact candidate argmin ----------------
// 1024 blocks (64 z-rows each), 256 threads = 4 waves.
__global__ __launch_bounds__(256) void gemm_argmin(const float* __restrict__ Z,
                                                   const float* __restrict__ E,
                                                   const float* __restrict__ Se,
                                                   int* __restrict__ idx_out,
                                                   int* __restrict__ full_list,
                                                   unsigned int* __restrict__ full_cnt) {
    __shared__ __align__(16) unsigned short Blds[64 * 264];  // 528B padded rows
    const int t  = threadIdx.x;
    const int w  = t >> 6;
    const int l  = t & 63;
    const int lo = l & 15;
    const int hi = l >> 4;
    const int m0 = blockIdx.x * 64;
    const int b  = m0 >> 10;
    const int hw = (m0 & 1023) + w * 16 + lo;
    const float* zs = Z + (size_t)b * 262144 + hw;

    // A-fragments: A[m=lo][k=hi*8+j], packed fp32->bf16 converts
    short8 af[8];
    #pragma unroll
    for (int ks = 0; ks < 8; ks++) {
        union { short8 s; unsigned int d[4]; } u;
        #pragma unroll
        for (int j = 0; j < 4; j++) {
            float a0 = zs[(ks * 32 + hi * 8 + 2 * j) * 1024];
            float a1 = zs[(ks * 32 + hi * 8 + 2 * j + 1) * 1024];
            u.d[j] = bf2bits(__float22bfloat162_rn(make_float2(a0, a1)));
        }
        af[ks] = u.s;
    }

    floatx4 acc[4];
    #pragma unroll
    for (int nf = 0; nf < 4; nf++) acc[nf] = (floatx4){0.f, 0.f, 0.f, 0.f};

    float v1[4], v2[4]; int i1[4];
    #pragma unroll
    for (int r = 0; r < 4; r++) { v1[r] = -1e30f; v2[r] = -1e30f; i1[r] = 0; }

    for (int nt = 0; nt < 16; nt++) {
        __syncthreads();
        const float* Eb = E + nt * 64 * 256;
        #pragma unroll
        for (int i = 0; i < 16; i++) {
            int chunk = i * 256 + t;
            int row = chunk >> 6, x = chunk & 63;
            float4 v = *(const float4*)(Eb + row * 256 + x * 4);
            unsigned int p0 = bf2bits(__float22bfloat162_rn(make_float2(v.x, v.y)));
            unsigned int p1 = bf2bits(__float22bfloat162_rn(make_float2(v.z, v.w)));
            *(uint2*)((char*)Blds + row * 528 + x * 8) = make_uint2(p0, p1);
        }
        __syncthreads();

        #pragma unroll
        for (int ks = 0; ks < 8; ks++) {
            #pragma unroll
            for (int nf = 0; nf < 4; nf++) {
                const short8* bp = (const short8*)((const char*)Blds +
                                    (nf * 16 + lo) * 528 + (ks * 32 + hi * 8) * 2);
                acc[nf] = __builtin_amdgcn_mfma_f32_16x16x32_bf16(af[ks], *bp, acc[nf], 0, 0, 0);
            }
        }

        #pragma unroll
        for (int nf = 0; nf < 4; nf++) {
            int n = nt * 64 + nf * 16 + lo;
            float h = 0.5f * Se[n];
            #pragma unroll
            for (int r = 0; r < 4; r++) {
                float s = acc[nf][r] - h;
                if (s > v1[r])      { v2[r] = v1[r]; v1[r] = s; i1[r] = n; }
                else if (s > v2[r]) { v2[r] = s; }
                acc[nf][r] = 0.f;
            }
        }
    }

    // per output row: merged top-1, ballots, candidate resolution
    for (int r = 0; r < 4; r++) {
        float a1 = v1[r]; int ai = i1[r];
        #pragma unroll
        for (int mask = 1; mask < 16; mask <<= 1) {
            float o1 = __shfl_xor(a1, mask);
            int   oi = __shfl_xor(ai, mask);
            if (o1 > a1 || (o1 == a1 && oi < ai)) { a1 = o1; ai = oi; }
        }
        float thresh = a1 - MARGIN;
        unsigned long long balF = __ballot(v2[r] >= thresh);
        unsigned long long balC = __ballot(v1[r] >= thresh);
        unsigned int fullq = (unsigned int)(balF >> (hi * 16)) & 0xFFFFu;
        unsigned int cm    = (unsigned int)(balC >> (hi * 16)) & 0xFFFFu;
        int m = __popc(cm);
        int row = m0 + w * 16 + hi * 4 + r;

        if (fullq) {
            // a lane may hide a 3rd+ candidate: full np-exact refine later
            if (lo == 0) {
                idx_out[row] = ai;  // placeholder, overwritten by refine_full
                unsigned int p = atomicAdd(full_cnt, 1u);
                if (p < FULL_CAP) full_list[p] = row;
            }
        } else if (m <= 1) {
            if (lo == 0) idx_out[row] = ai;
        } else {
            // candidate set == lane-top1s within margin (complete: any other k
            // would force its lane's top2 over thresh -> fullq). Evaluate
            // np-exactly: Sz (pairwise), dot (sequential FMA), fp32 rounding.
            const int row_hw = (m0 & 1023) + w * 16 + hi * 4 + r;
            const float* zr = Z + (size_t)b * 262144 + row_hw;
            const float* er = E + (size_t)i1[r] * 256;
            float dot = 0.f;
            float blk[2];
            #pragma unroll
            for (int h = 0; h < 2; h++) {
                float a8[8];
                #pragma unroll
                for (int q = 0; q < 8; q++) {
                    float zv = zr[(h * 128 + q) * 1024];
                    a8[q] = __fmul_rn(zv, zv);
                    dot = __fmaf_rn(zv, er[h * 128 + q], dot);
                }
                for (int i = 8; i < 128; i += 8) {
                    #pragma unroll
                    for (int q = 0; q < 8; q++) {
                        float zv = zr[(h * 128 + i + q) * 1024];
                        a8[q] = __fadd_rn(a8[q], __fmul_rn(zv, zv));
                        dot = __fmaf_rn(zv, er[h * 128 + i + q], dot);
                    }
                }
                blk[h] = __fadd_rn(__fadd_rn(__fadd_rn(a8[0], a8[1]), __fadd_rn(a8[2], a8[3])),
                                   __fadd_rn(__fadd_rn(a8[4], a8[5]), __fadd_rn(a8[6], a8[7])));
            }
            float Sz = __fadd_rn(blk[0], blk[1]);
            float dmy = 3.4e38f; int ky = 0x7fffffff;
            if ((cm >> lo) & 1u) {
                dmy = __fsub_rn(__fadd_rn(Sz, Se[i1[r]]), __fmul_rn(2.f, dot));
                ky = i1[r];
            }
            #pragma unroll
            for (int mask = 1; mask < 16; mask <<= 1) {
                float od = __shfl_xor(dmy, mask);
                int   ok = __shfl_xor(ky, mask);
                if (od < dmy || (od == dmy && ok < ky)) { dmy = od; ky = ok; }
            }
            if (lo == 0) idx_out[row] = ky;
        }
    }
}

// ---------------- kernel 3: LDS-staged full np-exact refine ----------------
// 16 rows per group; E staged in 32-row fp32 LDS tiles; stride 258 (2-way
// bank alias only). k ascending per thread, (d,k) lexicographic reduce ->
// np.argmin first-index semantics.
__global__ __launch_bounds__(256) void refine_full(const float* __restrict__ Z,
                                                   const float* __restrict__ E,
                                                   const float* __restrict__ Se,
                                                   const unsigned int* __restrict__ cnt,
                                                   const int* __restrict__ list,
                                                   int* __restrict__ idx_out) {
    __shared__ float zl[16 * 258];
    __shared__ float els[32 * 258];
    __shared__ float szs[16];
    __shared__ int rowid[16];
    unsigned int C = *cnt;
    if (C > FULL_CAP) C = FULL_CAP;
    const int t = threadIdx.x;
    const int kk = t & 31, rr = t >> 5;
    for (unsigned int base = blockIdx.x * 16; base < C; base += gridDim.x * 16) {
        int nrows = min(16, (int)(C - base));
        __syncthreads();
        if (t < 16) rowid[t] = list[base + (t < nrows ? t : 0)];
        __syncthreads();
        for (int i = 0; i < 16; i++) {
            int n = rowid[i];
            zl[i * 258 + t] = Z[(size_t)(n >> 10) * 262144 + t * 1024 + (n & 1023)];
        }
        __syncthreads();
        if (t < 16) szs[t] = np_pairwise_sumsq(&zl[t * 258]);

        float bd0 = 3.4e38f, bd1 = 3.4e38f; int bk0 = 0x7fffffff, bk1 = 0x7fffffff;
        for (int tile = 0; tile < 32; tile++) {
            __syncthreads();
            #pragma unroll
            for (int i = 0; i < 8; i++) {
                int chunk = i * 256 + t;
                int row = chunk >> 6, x = chunk & 63;
                float4 v = *(const float4*)(E + (tile * 32 + row) * 256 + x * 4);
                float* d = &els[row * 258 + x * 4];
                d[0] = v.x; d[1] = v.y; d[2] = v.z; d[3] = v.w;
            }
            __syncthreads();
            int k = tile * 32 + kk;
            const float* e  = &els[kk * 258];
            const float* za = &zl[rr * 258];
            const float* zb = &zl[(rr + 8) * 258];
            float a0 = 0.f, a1 = 0.f;
            for (int c = 0; c < 256; c += 2) {
                float2 e2 = *(const float2*)(e + c);
                float2 x2 = *(const float2*)(za + c);
                float2 y2 = *(const float2*)(zb + c);
                a0 = __fmaf_rn(x2.x, e2.x, a0); a0 = __fmaf_rn(x2.y, e2.y, a0);
                a1 = __fmaf_rn(y2.x, e2.x, a1); a1 = __fmaf_rn(y2.y, e2.y, a1);
            }
            float sek = Se[k];
            float d0 = __fsub_rn(__fadd_rn(szs[rr], sek),     __fmul_rn(2.f, a0));
            float d1 = __fsub_rn(__fadd_rn(szs[rr + 8], sek), __fmul_rn(2.f, a1));
            if (d0 < bd0) { bd0 = d0; bk0 = k; }
            if (d1 < bd1) { bd1 = d1; bk1 = k; }
        }
        #pragma unroll
        for (int mask = 1; mask < 32; mask <<= 1) {
            float od = __shfl_xor(bd0, mask); int ok = __shfl_xor(bk0, mask);
            if (od < bd0 || (od == bd0 && ok < bk0)) { bd0 = od; bk0 = ok; }
            od = __shfl_xor(bd1, mask); ok = __shfl_xor(bk1, mask);
            if (od < bd1 || (od == bd1 && ok < bk1)) { bd1 = od; bk1 = ok; }
        }
        if (kk == 0) {
            if (rr < nrows) idx_out[rowid[rr]] = bk0;
            if (rr + 8 < nrows) idx_out[rowid[rr + 8]] = bk1;
        }
    }
}

// ---------------- kernel 4: gather z_q (f32 out), fused loss ----------------
__global__ __launch_bounds__(256) void gather_loss(const float* __restrict__ Z,
                                                   const float* __restrict__ E,
                                                   const int* __restrict__ idx,
                                                   float* __restrict__ out,
                                                   float* __restrict__ loss) {
    __shared__ int nl[1024];
    __shared__ float rs[256];
    const int t = threadIdx.x;
    const int blk = blockIdx.x;
    const int e0 = blk * 8192;
    const int b = blk >> 5;
    #pragma unroll
    for (int i = 0; i < 4; i++) nl[t + i * 256] = idx[b * 1024 + t + i * 256];
    __syncthreads();
    float ls = 0.f;
    #pragma unroll 4
    for (int i = 0; i < 32; i++) {
        int e = e0 + i * 256 + t;
        int hw = e & 1023;
        int c  = (e >> 10) & 255;
        float q = E[nl[hw] * 256 + c];
        out[e] = q;
        float d = q - Z[e];
        ls += d * d;
    }
    rs[t] = ls; __syncthreads();
    for (int s = 128; s > 0; s >>= 1) { if (t < s) rs[t] += rs[t + s]; __syncthreads(); }
    if (t == 0) atomicAdd(loss, rs[0]);
}

// ---------------- kernel 5: finalize loss + indices i32 -> float in place ----------------
__global__ __launch_bounds__(256) void finalize(const float* __restrict__ loss,
                                                float* __restrict__ out) {
    int g = blockIdx.x * 256 + threadIdx.x;
    if (g == 0) out[16777216] = 1.25f * (*loss) / 16777216.f;
    int raw = ((const int*)(out + IDX_OFF))[g];
    out[IDX_OFF + g] = b2f(f2b((float)raw));  // bf16 round-trip matches bf16-cast ref
}

extern "C" void kernel_launch(void* const* d_in, const int* in_sizes, int n_in,
                              void* d_out, int out_size, void* d_ws, size_t ws_size,
                              hipStream_t stream) {
    const float* Z = (const float*)d_in[0];
    const float* E = (const float*)d_in[1];
    float* out = (float*)d_out;
    char* ws = (char*)d_ws;
    float*        loss = (float*)ws;
    unsigned int* cnt  = (unsigned int*)(ws + 4);
    float*        Se   = (float*)(ws + 64);
    int*          list = (int*)(ws + 4352);
    int*          idx  = (int*)(out + IDX_OFF);

    hipMemsetAsync(ws, 0, 8, stream);
    se_kernel<<<4, 256, 0, stream>>>(E, Se);
    gemm_argmin<<<1024, 256, 0, stream>>>(Z, E, Se, idx, list, cnt);
    refine_full<<<256, 256, 0, stream>>>(Z, E, Se, cnt, list, idx);
    gather_loss<<<2048, 256, 0, stream>>>(Z, E, idx, out, loss);
    finalize<<<256, 256, 0, stream>>>(loss, out);
}